// Round 12
// baseline (242.189 us; speedup 1.0000x reference)
//
#include <hip/hip_runtime.h>

// ---- problem constants ----
#define NN 25000          // nodes
#define NE 400000         // edges
#define NGR 64            // graphs
#define NB3 391           // (NN+63)/64 node-tile blocks
#define K1B 3125          // ceil(NN/8) blocks for xw precompute
#define HISTB 512         // blocks for fused hist part
#define EPS 1e-5f

// ---- workspace layout (floats) ----
static const size_t OFS_XWBUF  = 0;          // bf16[NN*1024] = 12.8M float-slots (51.2MB)
static const size_t OFS_H1     = 0;          // N*16 f32 (alias; xwbuf dead when k3 writes)
static const size_t OFS_XB2    = 12800000;   // N*16
static const size_t OFS_MSG    = 13200000;   // NE*16 (per-edge messages, CSC order)
static const size_t OFS_STATS  = 19600000;   // 2048 ([1216]=cnt1 [1217]=cnt2)
static const size_t OFS_EREC   = 19625600;   // NE*16: packed {ea[8], posl, pad} = one 64B line/edge
static const size_t OFS_OFF    = 26025600;   // 25600 (int)
static const size_t OFS_CSCOFF = 26051200;   // 25600 (int)
static const size_t OFS_OUTC   = 26076800;   // 25600 (int)
static const size_t OFS_INC    = 26102400;   // 25600 (int)
static const size_t OFS_BSUM   = 26128000;   // 512 (int)
static const size_t OFS_PART1  = 26128512;   // NB3*32
static const size_t OFS_PART2  = 26141024;   // NB3*32
// end 26,153,536 floats = 104.6 MB (ws >= 107.3MB proven round-1)
// stats: [32]scale1 [48]shift1 [96]scale2 [112]shift2 [128]gsum_raw(64*16) [1152]gcnt(64)

typedef __attribute__((ext_vector_type(8))) short v8s;   // 8 bf16 (4 VGPRs)
typedef __attribute__((ext_vector_type(4))) float v4f;   // MFMA accumulator

__device__ __forceinline__ void atomAddF(float* p, float v) { unsafeAtomicAdd(p, v); }

__device__ __forceinline__ float4 add4(float4 a, float4 b) {
  float4 r; r.x=a.x+b.x; r.y=a.y+b.y; r.z=a.z+b.z; r.w=a.w+b.w; return r;
}
__device__ __forceinline__ void fma4(float4& p, float r, const float4 a) {
  p.x += r*a.x; p.y += r*a.y; p.z += r*a.z; p.w += r*a.w;
}
__device__ __forceinline__ unsigned short f2bf(float f) {   // round-to-nearest-even
  unsigned u = __float_as_uint(f);
  u += 0x7FFFu + ((u >> 16) & 1u);
  return (unsigned short)(u >> 16);
}

// ---------------- fused: out/in histograms + per-node bf16 weight precompute ----------------
// xw half: 8 nodes/block, acc[8] (32 VGPR) for occupancy
__global__ __launch_bounds__(256) void k_hist_xw(const int* __restrict__ esrc,
    const int* __restrict__ edst, int* __restrict__ outc, int* __restrict__ inc,
    const float* __restrict__ x, const float* __restrict__ w2, const float* __restrict__ b2,
    unsigned short* __restrict__ xwbuf, float* __restrict__ xb2) {
  __shared__ float xs[8][17];
  if (blockIdx.x >= K1B) {
    const int base = (blockIdx.x - K1B)*256 + threadIdx.x;
    for (int e = base; e < NE; e += HISTB*256) {
      atomicAdd(&outc[esrc[e]], 1);
      atomicAdd(&inc[edst[e]], 1);
    }
    return;
  }
  const int t = threadIdx.x;
  const int h = t >> 2;              // 0..63
  const int og = (t & 3) * 4;        // 0,4,8,12
  const int nbase = blockIdx.x * 8;
  if (t < 128) {
    const int n = nbase + (t >> 4), i = t & 15;
    xs[t >> 4][i] = (n < NN) ? x[(size_t)n*16 + i] : 0.f;
  }
  __syncthreads();
  float4 acc[8];
  #pragma unroll
  for (int n = 0; n < 8; ++n) acc[n] = make_float4(0.f,0.f,0.f,0.f);
  #pragma unroll
  for (int i = 0; i < 16; ++i) {
    const float4 w = *reinterpret_cast<const float4*>(&w2[h*256 + i*16 + og]);
    #pragma unroll
    for (int n = 0; n < 8; ++n) fma4(acc[n], xs[n][i], w);
  }
  #pragma unroll
  for (int n = 0; n < 8; ++n) {
    const int nn = nbase + n;
    if (nn < NN) {
      ushort4 s4;
      s4.x = f2bf(acc[n].x); s4.y = f2bf(acc[n].y);
      s4.z = f2bf(acc[n].z); s4.w = f2bf(acc[n].w);
      *reinterpret_cast<ushort4*>(&xwbuf[(size_t)nn*1024 + h*16 + og]) = s4;
    }
  }
  if (t < 128) {
    const int n = nbase + (t >> 4), o = t & 15;
    if (n < NN) {
      float s = 0.f;
      #pragma unroll
      for (int i = 0; i < 16; ++i) s += xs[t >> 4][i] * b2[i*16 + o];
      xb2[(size_t)n*16 + o] = s;
    }
  }
}

// ---------------- multi-block scans ----------------
__global__ __launch_bounds__(256) void k0_scanA(const int* __restrict__ outc,
    const int* __restrict__ inc, int* __restrict__ bsum) {
  __shared__ int rO[256], rI[256];
  const int t = threadIdx.x;
  const int i = blockIdx.x*256 + t;
  rO[t] = outc[i];
  rI[t] = inc[i];
  __syncthreads();
  for (int st = 128; st > 0; st >>= 1) {
    if (t < st) { rO[t] += rO[t+st]; rI[t] += rI[t+st]; }
    __syncthreads();
  }
  if (t == 0) { bsum[blockIdx.x] = rO[0]; bsum[100 + blockIdx.x] = rI[0]; }
}

__global__ __launch_bounds__(128) void k0_scanB(int* __restrict__ bsum) {
  __shared__ int sO[128], sI[128];
  const int t = threadIdx.x;
  const int cO = (t < 100) ? bsum[t] : 0;
  const int cI = (t < 100) ? bsum[100 + t] : 0;
  sO[t] = cO; sI[t] = cI;
  __syncthreads();
  for (int st = 1; st < 128; st <<= 1) {
    const int vO = (t >= st) ? sO[t-st] : 0;
    const int vI = (t >= st) ? sI[t-st] : 0;
    __syncthreads();
    sO[t] += vO; sI[t] += vI;
    __syncthreads();
  }
  if (t < 100) { bsum[200 + t] = sO[t] - cO; bsum[300 + t] = sI[t] - cI; }
}

__global__ __launch_bounds__(256) void k0_scanC(int* __restrict__ outc,
    int* __restrict__ inc, const int* __restrict__ bsum,
    int* __restrict__ off, int* __restrict__ cscoff) {
  __shared__ int sO[256], sI[256];
  const int t = threadIdx.x;
  const int i = blockIdx.x*256 + t;
  const int cO = outc[i];
  const int cI = inc[i];
  sO[t] = cO; sI[t] = cI;
  __syncthreads();
  for (int st = 1; st < 256; st <<= 1) {
    const int vO = (t >= st) ? sO[t-st] : 0;
    const int vI = (t >= st) ? sI[t-st] : 0;
    __syncthreads();
    sO[t] += vO; sI[t] += vI;
    __syncthreads();
  }
  if (i <= NN) {
    off[i]    = sO[t] - cO + bsum[200 + blockIdx.x];
    cscoff[i] = sI[t] - cI + bsum[300 + blockIdx.x];
  }
  outc[i] = 0;
  inc[i]  = 0;
}

// fill: one FULL 64B record per edge {ea[8], posl, zero-pad} — fully-dirty line, no RMW
__global__ __launch_bounds__(256) void k0_fill(const int* __restrict__ esrc,
    const int* __restrict__ edst, const float* __restrict__ ea,
    int* __restrict__ curs, int* __restrict__ curd,
    const int* __restrict__ off, const int* __restrict__ cscoff,
    float* __restrict__ erec) {
  for (int e = blockIdx.x*blockDim.x + threadIdx.x; e < NE; e += gridDim.x*blockDim.x) {
    const int s = esrc[e], d = edst[e];
    const float4 a = *reinterpret_cast<const float4*>(&ea[(size_t)e*8]);
    const float4 b = *reinterpret_cast<const float4*>(&ea[(size_t)e*8 + 4]);
    const int c1 = atomicAdd(&curs[s], 1);
    const int c2 = atomicAdd(&curd[d], 1);
    float* r = &erec[(size_t)(off[s] + c1)*16];
    float4 c = make_float4(__int_as_float(cscoff[d] + c2), 0.f, 0.f, 0.f);
    float4 z = make_float4(0.f, 0.f, 0.f, 0.f);
    *reinterpret_cast<float4*>(r)      = a;
    *reinterpret_cast<float4*>(r + 4)  = b;
    *reinterpret_cast<float4*>(r + 8)  = c;
    *reinterpret_cast<float4*>(r + 12) = z;
  }
}

// ---------------- K2: layer-1 edge pass via MFMA ----------------
__global__ __launch_bounds__(256) void k2_csr(const float* __restrict__ erec,
    const float* __restrict__ w1, const float* __restrict__ b1,
    const unsigned short* __restrict__ xwbuf, const float* __restrict__ xb2,
    const int* __restrict__ off, float* __restrict__ msg) {
  __shared__ float w1s[512];
  __shared__ float b1s[64];
  for (int idx = threadIdx.x; idx < 512; idx += 256) w1s[idx] = w1[idx];
  if (threadIdx.x < 64) b1s[threadIdx.x] = b1[threadIdx.x];
  __syncthreads();
  const int lane = threadIdx.x & 63, wl = threadIdx.x >> 6;
  const int eidx = lane & 15;        // A row (edge in block) == D col (o)
  const int kg   = lane >> 4;        // k-group 0..3
  const int hb0  = kg*8;             // h base, first mfma (k=0..31)
  const int hb1  = 32 + kg*8;        // h base, second mfma (k=32..63)
  const int gw = blockIdx.x*4 + wl, nw = gridDim.x*4;

  for (int n = gw; n < NN; n += nw) {
    const int st = off[n];
    const int deg = off[n+1] - st;
    if (deg == 0) continue;
    const unsigned short* xwn = &xwbuf[(size_t)n*1024];
    v8s bf0, bf1;
    #pragma unroll
    for (int j = 0; j < 8; ++j) {
      bf0[j] = (short)xwn[(hb0 + j)*16 + eidx];
      bf1[j] = (short)xwn[(hb1 + j)*16 + eidx];
    }
    const float xbv = xb2[(size_t)n*16 + eidx];

    for (int j0 = 0; j0 < deg; j0 += 16) {
      const int jj = j0 + eidx;
      const int slot = st + ((jj < deg) ? jj : (deg - 1));
      const float* rec = &erec[(size_t)slot*16];
      const float4 ea0 = *reinterpret_cast<const float4*>(rec);
      const float4 ea1 = *reinterpret_cast<const float4*>(rec + 4);
      const int pe = *reinterpret_cast<const int*>(rec + 8);
      const float eav[8] = {ea0.x, ea0.y, ea0.z, ea0.w, ea1.x, ea1.y, ea1.z, ea1.w};
      float4 rA0 = *reinterpret_cast<const float4*>(&b1s[hb0]);
      float4 rA1 = *reinterpret_cast<const float4*>(&b1s[hb0 + 4]);
      float4 rB0 = *reinterpret_cast<const float4*>(&b1s[hb1]);
      float4 rB1 = *reinterpret_cast<const float4*>(&b1s[hb1 + 4]);
      #pragma unroll
      for (int f = 0; f < 8; ++f) {
        const float ef = eav[f];
        fma4(rA0, ef, *reinterpret_cast<const float4*>(&w1s[f*64 + hb0]));
        fma4(rA1, ef, *reinterpret_cast<const float4*>(&w1s[f*64 + hb0 + 4]));
        fma4(rB0, ef, *reinterpret_cast<const float4*>(&w1s[f*64 + hb1]));
        fma4(rB1, ef, *reinterpret_cast<const float4*>(&w1s[f*64 + hb1 + 4]));
      }
      v8s af0, af1;
      af0[0] = (short)f2bf(fmaxf(rA0.x, 0.f)); af0[1] = (short)f2bf(fmaxf(rA0.y, 0.f));
      af0[2] = (short)f2bf(fmaxf(rA0.z, 0.f)); af0[3] = (short)f2bf(fmaxf(rA0.w, 0.f));
      af0[4] = (short)f2bf(fmaxf(rA1.x, 0.f)); af0[5] = (short)f2bf(fmaxf(rA1.y, 0.f));
      af0[6] = (short)f2bf(fmaxf(rA1.z, 0.f)); af0[7] = (short)f2bf(fmaxf(rA1.w, 0.f));
      af1[0] = (short)f2bf(fmaxf(rB0.x, 0.f)); af1[1] = (short)f2bf(fmaxf(rB0.y, 0.f));
      af1[2] = (short)f2bf(fmaxf(rB0.z, 0.f)); af1[3] = (short)f2bf(fmaxf(rB0.w, 0.f));
      af1[4] = (short)f2bf(fmaxf(rB1.x, 0.f)); af1[5] = (short)f2bf(fmaxf(rB1.y, 0.f));
      af1[6] = (short)f2bf(fmaxf(rB1.z, 0.f)); af1[7] = (short)f2bf(fmaxf(rB1.w, 0.f));

      v4f acc = {0.f, 0.f, 0.f, 0.f};
      acc = __builtin_amdgcn_mfma_f32_16x16x32_bf16(af0, bf0, acc, 0, 0, 0);
      acc = __builtin_amdgcn_mfma_f32_16x16x32_bf16(af1, bf1, acc, 0, 0, 0);

      #pragma unroll
      for (int r = 0; r < 4; ++r) {
        const int er = kg*4 + r;
        const int pr = __shfl(pe, er);
        if (j0 + er < deg)
          msg[(size_t)pr*16 + eidx] = acc[r] + xbv;
      }
    }
  }
}

// ---------------- K3: reduce msg + x@root1 + bias1; BN1 partials; last block finalizes ----------------
__global__ __launch_bounds__(256) void k3_node1(const float* __restrict__ x,
    const float* __restrict__ root1, const float* __restrict__ bias1,
    const float* __restrict__ msg, const int* __restrict__ cscoff,
    const float* __restrict__ bn_g, const float* __restrict__ bn_b,
    float* __restrict__ h1, float* __restrict__ part,
    float* __restrict__ stats, int* __restrict__ cnt) {
  __shared__ float rt[256];
  __shared__ float red[2][64][16];
  __shared__ float fr[8][33];
  __shared__ int isLast;
  rt[threadIdx.x] = root1[threadIdx.x];
  const int nl = threadIdx.x >> 2, qd = threadIdx.x & 3;
  const int n = blockIdx.x*64 + nl;
  float4 s1 = {0,0,0,0}, s2 = {0,0,0,0};
  __syncthreads();
  if (n < NN) {
    const int b0 = cscoff[n];
    const int deg = cscoff[n+1] - b0;
    float4 sm = {0,0,0,0};
    for (int j = 0; j < deg; ++j)
      sm = add4(sm, *reinterpret_cast<const float4*>(&msg[(size_t)(b0+j)*16 + qd*4]));
    float4 acc = *reinterpret_cast<const float4*>(&bias1[qd*4]);
    #pragma unroll
    for (int i = 0; i < 16; ++i)
      fma4(acc, x[(size_t)n*16 + i], *reinterpret_cast<const float4*>(&rt[i*16 + qd*4]));
    const float inv = 1.f / (float)((deg > 0) ? deg : 1);
    fma4(acc, inv, sm);
    *reinterpret_cast<float4*>(&h1[(size_t)n*16 + qd*4]) = acc;
    s1 = acc;
    s2.x = acc.x*acc.x; s2.y = acc.y*acc.y; s2.z = acc.z*acc.z; s2.w = acc.w*acc.w;
  }
  *reinterpret_cast<float4*>(&red[0][nl][qd*4]) = s1;
  *reinterpret_cast<float4*>(&red[1][nl][qd*4]) = s2;
  __syncthreads();
  for (int st = 32; st > 0; st >>= 1) {
    if (nl < st) {
      #pragma unroll
      for (int k = 0; k < 4; ++k) {
        red[0][nl][qd*4+k] += red[0][nl+st][qd*4+k];
        red[1][nl][qd*4+k] += red[1][nl+st][qd*4+k];
      }
    }
    __syncthreads();
  }
  if (nl == 0) {
    *reinterpret_cast<float4*>(&part[blockIdx.x*32 + qd*4]) =
        *reinterpret_cast<const float4*>(&red[0][0][qd*4]);
    *reinterpret_cast<float4*>(&part[blockIdx.x*32 + 16 + qd*4]) =
        *reinterpret_cast<const float4*>(&red[1][0][qd*4]);
  }
  __syncthreads();
  if (threadIdx.x == 0) {
    __threadfence();
    isLast = (atomicAdd(cnt, 1) == NB3 - 1);
  }
  __syncthreads();
  if (!isLast) return;
  __threadfence();
  {
    const int o = threadIdx.x & 31, c = threadIdx.x >> 5;
    float s = 0.f;
    for (int blk = c; blk < NB3; blk += 8) s += part[blk*32 + o];
    fr[c][o] = s;
    __syncthreads();
    if (threadIdx.x < 32) {
      float tot = fr[0][threadIdx.x];
      for (int k = 1; k < 8; ++k) tot += fr[k][threadIdx.x];
      fr[0][threadIdx.x] = tot;
    }
    __syncthreads();
    if (threadIdx.x < 16) {
      const int oo = threadIdx.x;
      const float mean = fr[0][oo] / (float)NN;
      const float var  = fr[0][16+oo] / (float)NN - mean*mean;
      const float sc   = bn_g[oo] * rsqrtf(var + EPS);
      stats[32+oo] = sc;
      stats[48+oo] = bn_b[oo] - mean*sc;
    }
  }
}

// ---------------- K6: layer-2 edge pass (packed records) ----------------
__global__ __launch_bounds__(256) void k6_csr(const float* __restrict__ erec,
    const float* __restrict__ h1, const float* __restrict__ stats,
    const float* __restrict__ w, const float* __restrict__ bvec,
    const int* __restrict__ off, float* __restrict__ msg) {
  __shared__ float ws2[2048];
  __shared__ float bs2[256];
  __shared__ float hwS[4][128];
  __shared__ float hbS[4][32];
  for (int idx = threadIdx.x; idx < 2048; idx += 256) ws2[idx] = w[idx];
  bs2[threadIdx.x] = bvec[threadIdx.x];
  __syncthreads();
  const int lane = threadIdx.x & 63, wl = threadIdx.x >> 6;
  const int el = lane >> 2, q = lane & 3;
  const int f = lane >> 3, o2 = (lane & 7) * 2;
  const int gw = blockIdx.x*4 + wl, nw = gridDim.x*4;
  for (int n = gw; n < NN; n += nw) {
    const int st = off[n];
    const int deg = off[n+1] - st;
    if (deg == 0) continue;
    if (lane < 16)
      hbS[wl][lane] = h1[(size_t)n*16 + lane]*stats[32+lane] + stats[48+lane];
    __builtin_amdgcn_wave_barrier();
    float a0 = 0.f, a1 = 0.f;
    #pragma unroll
    for (int i = 0; i < 16; ++i) {
      const float hv = hbS[wl][i];
      a0 += hv * ws2[f*256 + i*16 + o2];
      a1 += hv * ws2[f*256 + i*16 + o2 + 1];
    }
    hwS[wl][f*16 + o2] = a0; hwS[wl][f*16 + o2 + 1] = a1;
    if (lane < 16) {
      float s = 0.f;
      #pragma unroll
      for (int i = 0; i < 16; ++i) s += hbS[wl][i] * bs2[i*16 + lane];
      hbS[wl][16 + lane] = s;
    }
    __builtin_amdgcn_wave_barrier();
    const float4 mb = *reinterpret_cast<const float4*>(&hbS[wl][16 + q*4]);
    for (int j0 = 0; j0 < deg; j0 += 16) {
      const int jj = j0 + el;
      const bool act = (jj < deg);
      const int slot = st + (act ? jj : 0);
      const float* rec = &erec[(size_t)slot*16];
      const float4 ea0 = *reinterpret_cast<const float4*>(rec);
      const float4 ea1 = *reinterpret_cast<const float4*>(rec + 4);
      const int pe = *reinterpret_cast<const int*>(rec + 8);
      const float ef[8] = {ea0.x, ea0.y, ea0.z, ea0.w, ea1.x, ea1.y, ea1.z, ea1.w};
      float4 m = mb;
      #pragma unroll
      for (int ff = 0; ff < 8; ++ff)
        fma4(m, ef[ff], *reinterpret_cast<const float4*>(&hwS[wl][ff*16 + q*4]));
      if (act)
        *reinterpret_cast<float4*>(&msg[(size_t)pe*16 + q*4]) = m;
    }
    __builtin_amdgcn_wave_barrier();   // protect hwS/hbS before next node's staging
  }
}

// ---------------- K7: reduce msg + bn1(h1)@root2 + bias2; pooling; last block finalizes BN2 ----------------
__global__ __launch_bounds__(256) void k7_node2(const float* __restrict__ h1,
    const float* __restrict__ root2, const float* __restrict__ bias2,
    const float* __restrict__ msg, const int* __restrict__ cscoff,
    const int* __restrict__ batch, const float* __restrict__ bn_g,
    const float* __restrict__ bn_b, float* __restrict__ stats,
    float* __restrict__ part, int* __restrict__ cnt) {
  __shared__ float rt[256];
  __shared__ float scs[16], shs[16];
  __shared__ float red[2][64][16];
  __shared__ float pool[64*17];
  __shared__ float fr[8][33];
  __shared__ int isLast;
  rt[threadIdx.x] = root2[threadIdx.x];
  if (threadIdx.x < 16) { scs[threadIdx.x] = stats[32+threadIdx.x]; shs[threadIdx.x] = stats[48+threadIdx.x]; }
  for (int idx = threadIdx.x; idx < 64*17; idx += 256) pool[idx] = 0.f;
  const int nl = threadIdx.x >> 2, qd = threadIdx.x & 3;
  const int n = blockIdx.x*64 + nl;
  float4 s1 = {0,0,0,0}, s2 = {0,0,0,0};
  __syncthreads();
  if (n < NN) {
    const int b0 = cscoff[n];
    const int deg = cscoff[n+1] - b0;
    float4 sm = {0,0,0,0};
    for (int j = 0; j < deg; ++j)
      sm = add4(sm, *reinterpret_cast<const float4*>(&msg[(size_t)(b0+j)*16 + qd*4]));
    float4 acc = *reinterpret_cast<const float4*>(&bias2[qd*4]);
    #pragma unroll
    for (int i = 0; i < 16; ++i) {
      const float hbn = h1[(size_t)n*16 + i]*scs[i] + shs[i];
      fma4(acc, hbn, *reinterpret_cast<const float4*>(&rt[i*16 + qd*4]));
    }
    const float inv = 1.f / (float)((deg > 0) ? deg : 1);
    fma4(acc, inv, sm);
    s1 = acc;
    s2.x = acc.x*acc.x; s2.y = acc.y*acc.y; s2.z = acc.z*acc.z; s2.w = acc.w*acc.w;
    const int g = batch[n];
    atomicAdd(&pool[g*17 + qd*4 + 0], acc.x);
    atomicAdd(&pool[g*17 + qd*4 + 1], acc.y);
    atomicAdd(&pool[g*17 + qd*4 + 2], acc.z);
    atomicAdd(&pool[g*17 + qd*4 + 3], acc.w);
    if (qd == 0) atomicAdd(&pool[g*17 + 16], 1.0f);
  }
  *reinterpret_cast<float4*>(&red[0][nl][qd*4]) = s1;
  *reinterpret_cast<float4*>(&red[1][nl][qd*4]) = s2;
  __syncthreads();
  for (int st = 32; st > 0; st >>= 1) {
    if (nl < st) {
      #pragma unroll
      for (int k = 0; k < 4; ++k) {
        red[0][nl][qd*4+k] += red[0][nl+st][qd*4+k];
        red[1][nl][qd*4+k] += red[1][nl+st][qd*4+k];
      }
    }
    __syncthreads();
  }
  if (nl == 0) {
    *reinterpret_cast<float4*>(&part[blockIdx.x*32 + qd*4]) =
        *reinterpret_cast<const float4*>(&red[0][0][qd*4]);
    *reinterpret_cast<float4*>(&part[blockIdx.x*32 + 16 + qd*4]) =
        *reinterpret_cast<const float4*>(&red[1][0][qd*4]);
  }
  for (int idx = threadIdx.x; idx < 64*17; idx += 256) {
    const float v = pool[idx];
    if (v != 0.f) {
      const int g = idx / 17, c = idx - g*17;
      atomAddF((c < 16) ? &stats[128 + g*16 + c] : &stats[1152 + g], v);
    }
  }
  __syncthreads();
  if (threadIdx.x == 0) {
    __threadfence();
    isLast = (atomicAdd(cnt, 1) == NB3 - 1);
  }
  __syncthreads();
  if (!isLast) return;
  __threadfence();
  {
    const int o = threadIdx.x & 31, c = threadIdx.x >> 5;
    float s = 0.f;
    for (int blk = c; blk < NB3; blk += 8) s += part[blk*32 + o];
    fr[c][o] = s;
    __syncthreads();
    if (threadIdx.x < 32) {
      float tot = fr[0][threadIdx.x];
      for (int k = 1; k < 8; ++k) tot += fr[k][threadIdx.x];
      fr[0][threadIdx.x] = tot;
    }
    __syncthreads();
    if (threadIdx.x < 16) {
      const int oo = threadIdx.x;
      const float mean = fr[0][oo] / (float)NN;
      const float var  = fr[0][16+oo] / (float)NN - mean*mean;
      const float sc   = bn_g[oo] * rsqrtf(var + EPS);
      stats[96+oo]  = sc;
      stats[112+oo] = bn_b[oo] - mean*sc;
    }
  }
}

// ---------------- K10: graph mean (raw) -> BN2 affine -> MLP head -> log_softmax ----------------
__global__ __launch_bounds__(128) void k10_head(const float* __restrict__ stats,
    const float* __restrict__ w1, const float* __restrict__ b1,
    const float* __restrict__ w2, const float* __restrict__ b2,
    float* __restrict__ out) {
  __shared__ float gm[16];
  __shared__ float a[128];
  __shared__ float l[10];
  __shared__ float mls[2];
  const int g = blockIdx.x, j = threadIdx.x;
  if (j < 16) {
    const float cnt = fmaxf(stats[1152 + g], 1.0f);
    gm[j] = (stats[128 + g*16 + j] / cnt) * stats[96 + j] + stats[112 + j];
  }
  __syncthreads();
  float s = b1[j];
  #pragma unroll
  for (int o = 0; o < 16; ++o) s += gm[o]*w1[o*128 + j];
  a[j] = fmaxf(s, 0.f);
  __syncthreads();
  if (j < 10) {
    float t = b2[j];
    #pragma unroll 16
    for (int k = 0; k < 128; ++k) t += a[k]*w2[k*10 + j];
    l[j] = t;
  }
  __syncthreads();
  if (j == 0) {
    float m = l[0];
    for (int c = 1; c < 10; ++c) m = fmaxf(m, l[c]);
    float se = 0.f;
    for (int c = 0; c < 10; ++c) se += expf(l[c]-m);
    mls[0] = m; mls[1] = logf(se);
  }
  __syncthreads();
  if (j < 10) out[g*10 + j] = l[j] - mls[0] - mls[1];
}

extern "C" void kernel_launch(void* const* d_in, const int* in_sizes, int n_in,
                              void* d_out, int out_size, void* d_ws, size_t ws_size,
                              hipStream_t stream) {
  const float* x      = (const float*)d_in[0];
  const int*   esrc   = (const int*)  d_in[1];
  const int*   edst   = (const int*)  d_in[2];
  const float* ea     = (const float*)d_in[3];
  const int*   batch  = (const int*)  d_in[4];
  const float* en1_w1 = (const float*)d_in[5];
  const float* en1_b1 = (const float*)d_in[6];
  const float* en1_w2 = (const float*)d_in[7];
  const float* en1_b2 = (const float*)d_in[8];
  const float* root1  = (const float*)d_in[9];
  const float* bias1  = (const float*)d_in[10];
  const float* bn1_g  = (const float*)d_in[11];
  const float* bn1_b  = (const float*)d_in[12];
  const float* en2_w  = (const float*)d_in[13];
  const float* en2_b  = (const float*)d_in[14];
  const float* root2  = (const float*)d_in[15];
  const float* bias2  = (const float*)d_in[16];
  const float* bn2_g  = (const float*)d_in[17];
  const float* bn2_b  = (const float*)d_in[18];
  const float* mlp_w1 = (const float*)d_in[19];
  const float* mlp_b1 = (const float*)d_in[20];
  const float* mlp_w2 = (const float*)d_in[21];
  const float* mlp_b2 = (const float*)d_in[22];
  float* out = (float*)d_out;
  float* ws  = (float*)d_ws;

  unsigned short* xwbuf = (unsigned short*)(ws + OFS_XWBUF);
  float* xb2    = ws + OFS_XB2;
  float* msg    = ws + OFS_MSG;
  float* stats  = ws + OFS_STATS;
  float* erec   = ws + OFS_EREC;
  float* h1     = ws + OFS_H1;
  float* part1  = ws + OFS_PART1;
  float* part2  = ws + OFS_PART2;
  int*   off    = (int*)(ws + OFS_OFF);
  int*   cscoff = (int*)(ws + OFS_CSCOFF);
  int*   outc   = (int*)(ws + OFS_OUTC);
  int*   inc    = (int*)(ws + OFS_INC);
  int*   bsum   = (int*)(ws + OFS_BSUM);
  int*   cnt1   = (int*)(stats + 1216);
  int*   cnt2   = (int*)(stats + 1217);

  hipMemsetAsync(outc,  0, 51200*sizeof(int), stream);    // outc + inc (adjacent)
  hipMemsetAsync(stats, 0, 2048*sizeof(float), stream);   // incl. cnt1/cnt2

  // fused histograms + bf16 per-node weight precompute (independent halves)
  hipLaunchKernelGGL(k_hist_xw, dim3(K1B + HISTB), dim3(256), 0, stream,
                     esrc, edst, outc, inc, x, en1_w2, en1_b2, xwbuf, xb2);
  hipLaunchKernelGGL(k0_scanA, dim3(100), dim3(256), 0, stream, outc, inc, bsum);
  hipLaunchKernelGGL(k0_scanB, dim3(1),   dim3(128), 0, stream, bsum);
  hipLaunchKernelGGL(k0_scanC, dim3(100), dim3(256), 0, stream, outc, inc, bsum, off, cscoff);
  hipLaunchKernelGGL(k0_fill,  dim3(1024),dim3(256), 0, stream, esrc, edst, ea, outc, inc,
                     off, cscoff, erec);

  // layer 1 (single pass over all nodes, MFMA edge kernel)
  hipLaunchKernelGGL(k2_csr,   dim3(1024), dim3(256), 0, stream, erec, en1_w1, en1_b1,
                     xwbuf, xb2, off, msg);
  hipLaunchKernelGGL(k3_node1, dim3(NB3),  dim3(256), 0, stream, x, root1, bias1, msg, cscoff,
                     bn1_g, bn1_b, h1, part1, stats, cnt1);

  // layer 2
  hipLaunchKernelGGL(k6_csr,   dim3(1024), dim3(256), 0, stream, erec, h1, stats,
                     en2_w, en2_b, off, msg);
  hipLaunchKernelGGL(k7_node2, dim3(NB3),  dim3(256), 0, stream, h1, root2, bias2, msg, cscoff,
                     batch, bn2_g, bn2_b, stats, part2, cnt2);

  // head
  hipLaunchKernelGGL(k10_head, dim3(64), dim3(128), 0, stream, stats, mlp_w1, mlp_b1, mlp_w2, mlp_b2, out);
}

// Round 13
// 225.339 us; speedup vs baseline: 1.0748x; 1.0748x over previous
//
#include <hip/hip_runtime.h>

// ---- problem constants ----
#define NN 25000          // nodes
#define NE 400000         // edges
#define NGR 64            // graphs
#define NB3 391           // (NN+63)/64 node-tile blocks
#define K1B 3125          // ceil(NN/8) blocks for xw precompute
#define NPAD 25600        // padded node count
#define EPS 1e-5f

// ---- workspace layout (floats) ----
static const size_t OFS_XWBUF  = 0;          // bf16[NN*1024] = 12.8M float-slots (51.2MB)
static const size_t OFS_H1     = 0;          // N*16 f32 (alias; xwbuf dead when k3 writes)
static const size_t OFS_XB2    = 12800000;   // N*16
static const size_t OFS_MSG    = 13200000;   // NE*16 (per-edge messages, CSC order)
// CSR-build scratch aliased into msg region (consumed before k2 writes msg):
static const size_t OFS_RANKS  = 13200000;   // NE int   (= msg + 0)
static const size_t OFS_RANKD  = 13600000;   // NE int   (= msg + 400000)
static const size_t OFS_OUTC8  = 14000000;   // 8*NPAD int (= msg + 800000)
static const size_t OFS_INC8   = 14204800;   // 8*NPAD int
static const size_t OFS_BASE8  = 14409600;   // 8*NPAD int
static const size_t OFS_CBASE8 = 14614400;   // 8*NPAD int
static const size_t OFS_STATS  = 19600000;   // 2048 ([1216]=cnt1 [1217]=cnt2)
static const size_t OFS_EREC   = 19625600;   // NE*16: packed {ea[8], posl, pad} = one 64B line/edge
static const size_t OFS_OFF    = 26025600;   // 25600 (int)
static const size_t OFS_CSCOFF = 26051200;   // 25600 (int)
static const size_t OFS_BSUM   = 26128000;   // 512 (int)
static const size_t OFS_PART1  = 26128512;   // NB3*32
static const size_t OFS_PART2  = 26141024;   // NB3*32
// end 26,153,536 floats = 104.6 MB (ws >= 107.3MB proven round-1)
// stats: [32]scale1 [48]shift1 [96]scale2 [112]shift2 [128]gsum_raw(64*16) [1152]gcnt(64)

typedef __attribute__((ext_vector_type(8))) short v8s;   // 8 bf16 (4 VGPRs)
typedef __attribute__((ext_vector_type(4))) float v4f;   // MFMA accumulator

__device__ __forceinline__ void atomAddF(float* p, float v) { unsafeAtomicAdd(p, v); }

__device__ __forceinline__ float4 add4(float4 a, float4 b) {
  float4 r; r.x=a.x+b.x; r.y=a.y+b.y; r.z=a.z+b.z; r.w=a.w+b.w; return r;
}
__device__ __forceinline__ void fma4(float4& p, float r, const float4 a) {
  p.x += r*a.x; p.y += r*a.y; p.z += r*a.z; p.w += r*a.w;
}
__device__ __forceinline__ unsigned short f2bf(float f) {   // round-to-nearest-even
  unsigned u = __float_as_uint(f);
  u += 0x7FFFu + ((u >> 16) & 1u);
  return (unsigned short)(u >> 16);
}

// ---------------- K1: per-node bf16 weight precompute (8 nodes/block) ----------------
__global__ __launch_bounds__(256) void k1_xw(const float* __restrict__ x,
    const float* __restrict__ w2, const float* __restrict__ b2,
    unsigned short* __restrict__ xwbuf, float* __restrict__ xb2) {
  __shared__ float xs[8][17];
  const int t = threadIdx.x;
  const int h = t >> 2;              // 0..63
  const int og = (t & 3) * 4;        // 0,4,8,12
  const int nbase = blockIdx.x * 8;
  if (t < 128) {
    const int n = nbase + (t >> 4), i = t & 15;
    xs[t >> 4][i] = (n < NN) ? x[(size_t)n*16 + i] : 0.f;
  }
  __syncthreads();
  float4 acc[8];
  #pragma unroll
  for (int n = 0; n < 8; ++n) acc[n] = make_float4(0.f,0.f,0.f,0.f);
  #pragma unroll
  for (int i = 0; i < 16; ++i) {
    const float4 w = *reinterpret_cast<const float4*>(&w2[h*256 + i*16 + og]);
    #pragma unroll
    for (int n = 0; n < 8; ++n) fma4(acc[n], xs[n][i], w);
  }
  #pragma unroll
  for (int n = 0; n < 8; ++n) {
    const int nn = nbase + n;
    if (nn < NN) {
      ushort4 s4;
      s4.x = f2bf(acc[n].x); s4.y = f2bf(acc[n].y);
      s4.z = f2bf(acc[n].z); s4.w = f2bf(acc[n].w);
      *reinterpret_cast<ushort4*>(&xwbuf[(size_t)nn*1024 + h*16 + og]) = s4;
    }
  }
  if (t < 128) {
    const int n = nbase + (t >> 4), o = t & 15;
    if (n < NN) {
      float s = 0.f;
      #pragma unroll
      for (int i = 0; i < 16; ++i) s += xs[t >> 4][i] * b2[i*16 + o];
      xb2[(size_t)n*16 + o] = s;
    }
  }
}

// ---------------- hist: 8 partition copies (p=blockIdx&7 ~ XCD) + per-edge rank record ----------------
__global__ __launch_bounds__(256) void k0_hist(const int* __restrict__ esrc,
    const int* __restrict__ edst, int* __restrict__ outc8, int* __restrict__ inc8,
    int* __restrict__ rankS, int* __restrict__ rankD) {
  const int p = blockIdx.x & 7;
  int* oc = outc8 + p*NPAD;
  int* ic = inc8  + p*NPAD;
  for (int e = blockIdx.x*256 + threadIdx.x; e < NE; e += gridDim.x*256) {
    const int c1 = atomicAdd(&oc[esrc[e]], 1);
    const int c2 = atomicAdd(&ic[edst[e]], 1);
    rankS[e] = (p << 28) | c1;
    rankD[e] = (p << 28) | c2;
  }
}

// ---------------- multi-block scans over per-node totals ----------------
__global__ __launch_bounds__(256) void k0_scanA(const int* __restrict__ outc8,
    const int* __restrict__ inc8, int* __restrict__ bsum) {
  __shared__ int rO[256], rI[256];
  const int t = threadIdx.x;
  const int i = blockIdx.x*256 + t;
  int s = 0, si = 0;
  #pragma unroll
  for (int p = 0; p < 8; ++p) { s += outc8[p*NPAD + i]; si += inc8[p*NPAD + i]; }
  rO[t] = s; rI[t] = si;
  __syncthreads();
  for (int st = 128; st > 0; st >>= 1) {
    if (t < st) { rO[t] += rO[t+st]; rI[t] += rI[t+st]; }
    __syncthreads();
  }
  if (t == 0) { bsum[blockIdx.x] = rO[0]; bsum[100 + blockIdx.x] = rI[0]; }
}

__global__ __launch_bounds__(128) void k0_scanB(int* __restrict__ bsum) {
  __shared__ int sO[128], sI[128];
  const int t = threadIdx.x;
  const int cO = (t < 100) ? bsum[t] : 0;
  const int cI = (t < 100) ? bsum[100 + t] : 0;
  sO[t] = cO; sI[t] = cI;
  __syncthreads();
  for (int st = 1; st < 128; st <<= 1) {
    const int vO = (t >= st) ? sO[t-st] : 0;
    const int vI = (t >= st) ? sI[t-st] : 0;
    __syncthreads();
    sO[t] += vO; sI[t] += vI;
    __syncthreads();
  }
  if (t < 100) { bsum[200 + t] = sO[t] - cO; bsum[300 + t] = sI[t] - cI; }
}

// scanC: node-level exclusive scan -> off/cscoff; per-(node,partition) bases
__global__ __launch_bounds__(256) void k0_scanC(const int* __restrict__ outc8,
    const int* __restrict__ inc8, const int* __restrict__ bsum,
    int* __restrict__ off, int* __restrict__ cscoff,
    int* __restrict__ base8, int* __restrict__ cbase8) {
  __shared__ int sO[256], sI[256];
  const int t = threadIdx.x;
  const int i = blockIdx.x*256 + t;
  int co[8], ci[8];
  int cO = 0, cI = 0;
  #pragma unroll
  for (int p = 0; p < 8; ++p) {
    co[p] = outc8[p*NPAD + i]; cO += co[p];
    ci[p] = inc8[p*NPAD + i];  cI += ci[p];
  }
  sO[t] = cO; sI[t] = cI;
  __syncthreads();
  for (int st = 1; st < 256; st <<= 1) {
    const int vO = (t >= st) ? sO[t-st] : 0;
    const int vI = (t >= st) ? sI[t-st] : 0;
    __syncthreads();
    sO[t] += vO; sI[t] += vI;
    __syncthreads();
  }
  const int offv = sO[t] - cO + bsum[200 + blockIdx.x];
  const int cscv = sI[t] - cI + bsum[300 + blockIdx.x];
  if (i <= NN) { off[i] = offv; cscoff[i] = cscv; }
  int run = offv;
  #pragma unroll
  for (int p = 0; p < 8; ++p) { base8[p*NPAD + i] = run; run += co[p]; }
  run = cscv;
  #pragma unroll
  for (int p = 0; p < 8; ++p) { cbase8[p*NPAD + i] = run; run += ci[p]; }
}

// fill: NO atomics — slot/pos derived from recorded rank + scanned bases
__global__ __launch_bounds__(256) void k0_fill(const int* __restrict__ esrc,
    const int* __restrict__ edst, const float* __restrict__ ea,
    const int* __restrict__ rankS, const int* __restrict__ rankD,
    const int* __restrict__ base8, const int* __restrict__ cbase8,
    float* __restrict__ erec) {
  for (int e = blockIdx.x*blockDim.x + threadIdx.x; e < NE; e += gridDim.x*blockDim.x) {
    const int s = esrc[e], d = edst[e];
    const float4 a = *reinterpret_cast<const float4*>(&ea[(size_t)e*8]);
    const float4 b = *reinterpret_cast<const float4*>(&ea[(size_t)e*8 + 4]);
    const int rs = rankS[e], rd = rankD[e];
    const int slot = base8[(rs >> 28)*NPAD + s] + (rs & 0x0FFFFFFF);
    const int pos  = cbase8[(rd >> 28)*NPAD + d] + (rd & 0x0FFFFFFF);
    float* r = &erec[(size_t)slot*16];
    const float4 c = make_float4(__int_as_float(pos), 0.f, 0.f, 0.f);
    const float4 z = make_float4(0.f, 0.f, 0.f, 0.f);
    *reinterpret_cast<float4*>(r)      = a;
    *reinterpret_cast<float4*>(r + 4)  = b;
    *reinterpret_cast<float4*>(r + 8)  = c;
    *reinterpret_cast<float4*>(r + 12) = z;
  }
}

// ---------------- K2: layer-1 edge pass via MFMA ----------------
__global__ __launch_bounds__(256) void k2_csr(const float* __restrict__ erec,
    const float* __restrict__ w1, const float* __restrict__ b1,
    const unsigned short* __restrict__ xwbuf, const float* __restrict__ xb2,
    const int* __restrict__ off, float* __restrict__ msg) {
  __shared__ float w1s[512];
  __shared__ float b1s[64];
  for (int idx = threadIdx.x; idx < 512; idx += 256) w1s[idx] = w1[idx];
  if (threadIdx.x < 64) b1s[threadIdx.x] = b1[threadIdx.x];
  __syncthreads();
  const int lane = threadIdx.x & 63, wl = threadIdx.x >> 6;
  const int eidx = lane & 15;        // A row (edge in block) == D col (o)
  const int kg   = lane >> 4;        // k-group 0..3
  const int hb0  = kg*8;             // h base, first mfma (k=0..31)
  const int hb1  = 32 + kg*8;        // h base, second mfma (k=32..63)
  const int gw = blockIdx.x*4 + wl, nw = gridDim.x*4;

  for (int n = gw; n < NN; n += nw) {
    const int st = off[n];
    const int deg = off[n+1] - st;
    if (deg == 0) continue;
    const unsigned short* xwn = &xwbuf[(size_t)n*1024];
    v8s bf0, bf1;
    #pragma unroll
    for (int j = 0; j < 8; ++j) {
      bf0[j] = (short)xwn[(hb0 + j)*16 + eidx];
      bf1[j] = (short)xwn[(hb1 + j)*16 + eidx];
    }
    const float xbv = xb2[(size_t)n*16 + eidx];

    for (int j0 = 0; j0 < deg; j0 += 16) {
      const int jj = j0 + eidx;
      const int slot = st + ((jj < deg) ? jj : (deg - 1));
      const float* rec = &erec[(size_t)slot*16];
      const float4 ea0 = *reinterpret_cast<const float4*>(rec);
      const float4 ea1 = *reinterpret_cast<const float4*>(rec + 4);
      const int pe = *reinterpret_cast<const int*>(rec + 8);
      const float eav[8] = {ea0.x, ea0.y, ea0.z, ea0.w, ea1.x, ea1.y, ea1.z, ea1.w};
      float4 rA0 = *reinterpret_cast<const float4*>(&b1s[hb0]);
      float4 rA1 = *reinterpret_cast<const float4*>(&b1s[hb0 + 4]);
      float4 rB0 = *reinterpret_cast<const float4*>(&b1s[hb1]);
      float4 rB1 = *reinterpret_cast<const float4*>(&b1s[hb1 + 4]);
      #pragma unroll
      for (int f = 0; f < 8; ++f) {
        const float ef = eav[f];
        fma4(rA0, ef, *reinterpret_cast<const float4*>(&w1s[f*64 + hb0]));
        fma4(rA1, ef, *reinterpret_cast<const float4*>(&w1s[f*64 + hb0 + 4]));
        fma4(rB0, ef, *reinterpret_cast<const float4*>(&w1s[f*64 + hb1]));
        fma4(rB1, ef, *reinterpret_cast<const float4*>(&w1s[f*64 + hb1 + 4]));
      }
      v8s af0, af1;
      af0[0] = (short)f2bf(fmaxf(rA0.x, 0.f)); af0[1] = (short)f2bf(fmaxf(rA0.y, 0.f));
      af0[2] = (short)f2bf(fmaxf(rA0.z, 0.f)); af0[3] = (short)f2bf(fmaxf(rA0.w, 0.f));
      af0[4] = (short)f2bf(fmaxf(rA1.x, 0.f)); af0[5] = (short)f2bf(fmaxf(rA1.y, 0.f));
      af0[6] = (short)f2bf(fmaxf(rA1.z, 0.f)); af0[7] = (short)f2bf(fmaxf(rA1.w, 0.f));
      af1[0] = (short)f2bf(fmaxf(rB0.x, 0.f)); af1[1] = (short)f2bf(fmaxf(rB0.y, 0.f));
      af1[2] = (short)f2bf(fmaxf(rB0.z, 0.f)); af1[3] = (short)f2bf(fmaxf(rB0.w, 0.f));
      af1[4] = (short)f2bf(fmaxf(rB1.x, 0.f)); af1[5] = (short)f2bf(fmaxf(rB1.y, 0.f));
      af1[6] = (short)f2bf(fmaxf(rB1.z, 0.f)); af1[7] = (short)f2bf(fmaxf(rB1.w, 0.f));

      v4f acc = {0.f, 0.f, 0.f, 0.f};
      acc = __builtin_amdgcn_mfma_f32_16x16x32_bf16(af0, bf0, acc, 0, 0, 0);
      acc = __builtin_amdgcn_mfma_f32_16x16x32_bf16(af1, bf1, acc, 0, 0, 0);

      #pragma unroll
      for (int r = 0; r < 4; ++r) {
        const int er = kg*4 + r;
        const int pr = __shfl(pe, er);
        if (j0 + er < deg)
          msg[(size_t)pr*16 + eidx] = acc[r] + xbv;
      }
    }
  }
}

// ---------------- K3: reduce msg + x@root1 + bias1; BN1 partials; last block finalizes ----------------
__global__ __launch_bounds__(256) void k3_node1(const float* __restrict__ x,
    const float* __restrict__ root1, const float* __restrict__ bias1,
    const float* __restrict__ msg, const int* __restrict__ cscoff,
    const float* __restrict__ bn_g, const float* __restrict__ bn_b,
    float* __restrict__ h1, float* __restrict__ part,
    float* __restrict__ stats, int* __restrict__ cnt) {
  __shared__ float rt[256];
  __shared__ float red[2][64][16];
  __shared__ float fr[8][33];
  __shared__ int isLast;
  rt[threadIdx.x] = root1[threadIdx.x];
  const int nl = threadIdx.x >> 2, qd = threadIdx.x & 3;
  const int n = blockIdx.x*64 + nl;
  float4 s1 = {0,0,0,0}, s2 = {0,0,0,0};
  __syncthreads();
  if (n < NN) {
    const int b0 = cscoff[n];
    const int deg = cscoff[n+1] - b0;
    float4 sm = {0,0,0,0};
    for (int j = 0; j < deg; ++j)
      sm = add4(sm, *reinterpret_cast<const float4*>(&msg[(size_t)(b0+j)*16 + qd*4]));
    float4 acc = *reinterpret_cast<const float4*>(&bias1[qd*4]);
    #pragma unroll
    for (int i = 0; i < 16; ++i)
      fma4(acc, x[(size_t)n*16 + i], *reinterpret_cast<const float4*>(&rt[i*16 + qd*4]));
    const float inv = 1.f / (float)((deg > 0) ? deg : 1);
    fma4(acc, inv, sm);
    *reinterpret_cast<float4*>(&h1[(size_t)n*16 + qd*4]) = acc;
    s1 = acc;
    s2.x = acc.x*acc.x; s2.y = acc.y*acc.y; s2.z = acc.z*acc.z; s2.w = acc.w*acc.w;
  }
  *reinterpret_cast<float4*>(&red[0][nl][qd*4]) = s1;
  *reinterpret_cast<float4*>(&red[1][nl][qd*4]) = s2;
  __syncthreads();
  for (int st = 32; st > 0; st >>= 1) {
    if (nl < st) {
      #pragma unroll
      for (int k = 0; k < 4; ++k) {
        red[0][nl][qd*4+k] += red[0][nl+st][qd*4+k];
        red[1][nl][qd*4+k] += red[1][nl+st][qd*4+k];
      }
    }
    __syncthreads();
  }
  if (nl == 0) {
    *reinterpret_cast<float4*>(&part[blockIdx.x*32 + qd*4]) =
        *reinterpret_cast<const float4*>(&red[0][0][qd*4]);
    *reinterpret_cast<float4*>(&part[blockIdx.x*32 + 16 + qd*4]) =
        *reinterpret_cast<const float4*>(&red[1][0][qd*4]);
  }
  __syncthreads();
  if (threadIdx.x == 0) {
    __threadfence();
    isLast = (atomicAdd(cnt, 1) == NB3 - 1);
  }
  __syncthreads();
  if (!isLast) return;
  __threadfence();
  {
    const int o = threadIdx.x & 31, c = threadIdx.x >> 5;
    float s = 0.f;
    for (int blk = c; blk < NB3; blk += 8) s += part[blk*32 + o];
    fr[c][o] = s;
    __syncthreads();
    if (threadIdx.x < 32) {
      float tot = fr[0][threadIdx.x];
      for (int k = 1; k < 8; ++k) tot += fr[k][threadIdx.x];
      fr[0][threadIdx.x] = tot;
    }
    __syncthreads();
    if (threadIdx.x < 16) {
      const int oo = threadIdx.x;
      const float mean = fr[0][oo] / (float)NN;
      const float var  = fr[0][16+oo] / (float)NN - mean*mean;
      const float sc   = bn_g[oo] * rsqrtf(var + EPS);
      stats[32+oo] = sc;
      stats[48+oo] = bn_b[oo] - mean*sc;
    }
  }
}

// ---------------- K6: layer-2 edge pass (packed records) ----------------
__global__ __launch_bounds__(256) void k6_csr(const float* __restrict__ erec,
    const float* __restrict__ h1, const float* __restrict__ stats,
    const float* __restrict__ w, const float* __restrict__ bvec,
    const int* __restrict__ off, float* __restrict__ msg) {
  __shared__ float ws2[2048];
  __shared__ float bs2[256];
  __shared__ float hwS[4][128];
  __shared__ float hbS[4][32];
  for (int idx = threadIdx.x; idx < 2048; idx += 256) ws2[idx] = w[idx];
  bs2[threadIdx.x] = bvec[threadIdx.x];
  __syncthreads();
  const int lane = threadIdx.x & 63, wl = threadIdx.x >> 6;
  const int el = lane >> 2, q = lane & 3;
  const int f = lane >> 3, o2 = (lane & 7) * 2;
  const int gw = blockIdx.x*4 + wl, nw = gridDim.x*4;
  for (int n = gw; n < NN; n += nw) {
    const int st = off[n];
    const int deg = off[n+1] - st;
    if (deg == 0) continue;
    if (lane < 16)
      hbS[wl][lane] = h1[(size_t)n*16 + lane]*stats[32+lane] + stats[48+lane];
    __builtin_amdgcn_wave_barrier();
    float a0 = 0.f, a1 = 0.f;
    #pragma unroll
    for (int i = 0; i < 16; ++i) {
      const float hv = hbS[wl][i];
      a0 += hv * ws2[f*256 + i*16 + o2];
      a1 += hv * ws2[f*256 + i*16 + o2 + 1];
    }
    hwS[wl][f*16 + o2] = a0; hwS[wl][f*16 + o2 + 1] = a1;
    if (lane < 16) {
      float s = 0.f;
      #pragma unroll
      for (int i = 0; i < 16; ++i) s += hbS[wl][i] * bs2[i*16 + lane];
      hbS[wl][16 + lane] = s;
    }
    __builtin_amdgcn_wave_barrier();
    const float4 mb = *reinterpret_cast<const float4*>(&hbS[wl][16 + q*4]);
    for (int j0 = 0; j0 < deg; j0 += 16) {
      const int jj = j0 + el;
      const bool act = (jj < deg);
      const int slot = st + (act ? jj : 0);
      const float* rec = &erec[(size_t)slot*16];
      const float4 ea0 = *reinterpret_cast<const float4*>(rec);
      const float4 ea1 = *reinterpret_cast<const float4*>(rec + 4);
      const int pe = *reinterpret_cast<const int*>(rec + 8);
      const float ef[8] = {ea0.x, ea0.y, ea0.z, ea0.w, ea1.x, ea1.y, ea1.z, ea1.w};
      float4 m = mb;
      #pragma unroll
      for (int ff = 0; ff < 8; ++ff)
        fma4(m, ef[ff], *reinterpret_cast<const float4*>(&hwS[wl][ff*16 + q*4]));
      if (act)
        *reinterpret_cast<float4*>(&msg[(size_t)pe*16 + q*4]) = m;
    }
    __builtin_amdgcn_wave_barrier();   // protect hwS/hbS before next node's staging
  }
}

// ---------------- K7: reduce msg + bn1(h1)@root2 + bias2; pooling; last block finalizes BN2 ----------------
__global__ __launch_bounds__(256) void k7_node2(const float* __restrict__ h1,
    const float* __restrict__ root2, const float* __restrict__ bias2,
    const float* __restrict__ msg, const int* __restrict__ cscoff,
    const int* __restrict__ batch, const float* __restrict__ bn_g,
    const float* __restrict__ bn_b, float* __restrict__ stats,
    float* __restrict__ part, int* __restrict__ cnt) {
  __shared__ float rt[256];
  __shared__ float scs[16], shs[16];
  __shared__ float red[2][64][16];
  __shared__ float pool[64*17];
  __shared__ float fr[8][33];
  __shared__ int isLast;
  rt[threadIdx.x] = root2[threadIdx.x];
  if (threadIdx.x < 16) { scs[threadIdx.x] = stats[32+threadIdx.x]; shs[threadIdx.x] = stats[48+threadIdx.x]; }
  for (int idx = threadIdx.x; idx < 64*17; idx += 256) pool[idx] = 0.f;
  const int nl = threadIdx.x >> 2, qd = threadIdx.x & 3;
  const int n = blockIdx.x*64 + nl;
  float4 s1 = {0,0,0,0}, s2 = {0,0,0,0};
  __syncthreads();
  if (n < NN) {
    const int b0 = cscoff[n];
    const int deg = cscoff[n+1] - b0;
    float4 sm = {0,0,0,0};
    for (int j = 0; j < deg; ++j)
      sm = add4(sm, *reinterpret_cast<const float4*>(&msg[(size_t)(b0+j)*16 + qd*4]));
    float4 acc = *reinterpret_cast<const float4*>(&bias2[qd*4]);
    #pragma unroll
    for (int i = 0; i < 16; ++i) {
      const float hbn = h1[(size_t)n*16 + i]*scs[i] + shs[i];
      fma4(acc, hbn, *reinterpret_cast<const float4*>(&rt[i*16 + qd*4]));
    }
    const float inv = 1.f / (float)((deg > 0) ? deg : 1);
    fma4(acc, inv, sm);
    s1 = acc;
    s2.x = acc.x*acc.x; s2.y = acc.y*acc.y; s2.z = acc.z*acc.z; s2.w = acc.w*acc.w;
    const int g = batch[n];
    atomicAdd(&pool[g*17 + qd*4 + 0], acc.x);
    atomicAdd(&pool[g*17 + qd*4 + 1], acc.y);
    atomicAdd(&pool[g*17 + qd*4 + 2], acc.z);
    atomicAdd(&pool[g*17 + qd*4 + 3], acc.w);
    if (qd == 0) atomicAdd(&pool[g*17 + 16], 1.0f);
  }
  *reinterpret_cast<float4*>(&red[0][nl][qd*4]) = s1;
  *reinterpret_cast<float4*>(&red[1][nl][qd*4]) = s2;
  __syncthreads();
  for (int st = 32; st > 0; st >>= 1) {
    if (nl < st) {
      #pragma unroll
      for (int k = 0; k < 4; ++k) {
        red[0][nl][qd*4+k] += red[0][nl+st][qd*4+k];
        red[1][nl][qd*4+k] += red[1][nl+st][qd*4+k];
      }
    }
    __syncthreads();
  }
  if (nl == 0) {
    *reinterpret_cast<float4*>(&part[blockIdx.x*32 + qd*4]) =
        *reinterpret_cast<const float4*>(&red[0][0][qd*4]);
    *reinterpret_cast<float4*>(&part[blockIdx.x*32 + 16 + qd*4]) =
        *reinterpret_cast<const float4*>(&red[1][0][qd*4]);
  }
  for (int idx = threadIdx.x; idx < 64*17; idx += 256) {
    const float v = pool[idx];
    if (v != 0.f) {
      const int g = idx / 17, c = idx - g*17;
      atomAddF((c < 16) ? &stats[128 + g*16 + c] : &stats[1152 + g], v);
    }
  }
  __syncthreads();
  if (threadIdx.x == 0) {
    __threadfence();
    isLast = (atomicAdd(cnt, 1) == NB3 - 1);
  }
  __syncthreads();
  if (!isLast) return;
  __threadfence();
  {
    const int o = threadIdx.x & 31, c = threadIdx.x >> 5;
    float s = 0.f;
    for (int blk = c; blk < NB3; blk += 8) s += part[blk*32 + o];
    fr[c][o] = s;
    __syncthreads();
    if (threadIdx.x < 32) {
      float tot = fr[0][threadIdx.x];
      for (int k = 1; k < 8; ++k) tot += fr[k][threadIdx.x];
      fr[0][threadIdx.x] = tot;
    }
    __syncthreads();
    if (threadIdx.x < 16) {
      const int oo = threadIdx.x;
      const float mean = fr[0][oo] / (float)NN;
      const float var  = fr[0][16+oo] / (float)NN - mean*mean;
      const float sc   = bn_g[oo] * rsqrtf(var + EPS);
      stats[96+oo]  = sc;
      stats[112+oo] = bn_b[oo] - mean*sc;
    }
  }
}

// ---------------- K10: graph mean (raw) -> BN2 affine -> MLP head -> log_softmax ----------------
__global__ __launch_bounds__(128) void k10_head(const float* __restrict__ stats,
    const float* __restrict__ w1, const float* __restrict__ b1,
    const float* __restrict__ w2, const float* __restrict__ b2,
    float* __restrict__ out) {
  __shared__ float gm[16];
  __shared__ float a[128];
  __shared__ float l[10];
  __shared__ float mls[2];
  const int g = blockIdx.x, j = threadIdx.x;
  if (j < 16) {
    const float cnt = fmaxf(stats[1152 + g], 1.0f);
    gm[j] = (stats[128 + g*16 + j] / cnt) * stats[96 + j] + stats[112 + j];
  }
  __syncthreads();
  float s = b1[j];
  #pragma unroll
  for (int o = 0; o < 16; ++o) s += gm[o]*w1[o*128 + j];
  a[j] = fmaxf(s, 0.f);
  __syncthreads();
  if (j < 10) {
    float t = b2[j];
    #pragma unroll 16
    for (int k = 0; k < 128; ++k) t += a[k]*w2[k*10 + j];
    l[j] = t;
  }
  __syncthreads();
  if (j == 0) {
    float m = l[0];
    for (int c = 1; c < 10; ++c) m = fmaxf(m, l[c]);
    float se = 0.f;
    for (int c = 0; c < 10; ++c) se += expf(l[c]-m);
    mls[0] = m; mls[1] = logf(se);
  }
  __syncthreads();
  if (j < 10) out[g*10 + j] = l[j] - mls[0] - mls[1];
}

extern "C" void kernel_launch(void* const* d_in, const int* in_sizes, int n_in,
                              void* d_out, int out_size, void* d_ws, size_t ws_size,
                              hipStream_t stream) {
  const float* x      = (const float*)d_in[0];
  const int*   esrc   = (const int*)  d_in[1];
  const int*   edst   = (const int*)  d_in[2];
  const float* ea     = (const float*)d_in[3];
  const int*   batch  = (const int*)  d_in[4];
  const float* en1_w1 = (const float*)d_in[5];
  const float* en1_b1 = (const float*)d_in[6];
  const float* en1_w2 = (const float*)d_in[7];
  const float* en1_b2 = (const float*)d_in[8];
  const float* root1  = (const float*)d_in[9];
  const float* bias1  = (const float*)d_in[10];
  const float* bn1_g  = (const float*)d_in[11];
  const float* bn1_b  = (const float*)d_in[12];
  const float* en2_w  = (const float*)d_in[13];
  const float* en2_b  = (const float*)d_in[14];
  const float* root2  = (const float*)d_in[15];
  const float* bias2  = (const float*)d_in[16];
  const float* bn2_g  = (const float*)d_in[17];
  const float* bn2_b  = (const float*)d_in[18];
  const float* mlp_w1 = (const float*)d_in[19];
  const float* mlp_b1 = (const float*)d_in[20];
  const float* mlp_w2 = (const float*)d_in[21];
  const float* mlp_b2 = (const float*)d_in[22];
  float* out = (float*)d_out;
  float* ws  = (float*)d_ws;

  unsigned short* xwbuf = (unsigned short*)(ws + OFS_XWBUF);
  float* xb2    = ws + OFS_XB2;
  float* msg    = ws + OFS_MSG;
  float* stats  = ws + OFS_STATS;
  float* erec   = ws + OFS_EREC;
  float* h1     = ws + OFS_H1;
  float* part1  = ws + OFS_PART1;
  float* part2  = ws + OFS_PART2;
  int*   rankS  = (int*)(ws + OFS_RANKS);
  int*   rankD  = (int*)(ws + OFS_RANKD);
  int*   outc8  = (int*)(ws + OFS_OUTC8);
  int*   inc8   = (int*)(ws + OFS_INC8);
  int*   base8  = (int*)(ws + OFS_BASE8);
  int*   cbase8 = (int*)(ws + OFS_CBASE8);
  int*   off    = (int*)(ws + OFS_OFF);
  int*   cscoff = (int*)(ws + OFS_CSCOFF);
  int*   bsum   = (int*)(ws + OFS_BSUM);
  int*   cnt1   = (int*)(stats + 1216);
  int*   cnt2   = (int*)(stats + 1217);

  hipMemsetAsync(outc8, 0, 2*8*NPAD*sizeof(int), stream);  // outc8 + inc8 (adjacent)
  hipMemsetAsync(stats, 0, 2048*sizeof(float), stream);    // incl. cnt1/cnt2

  // per-node bf16 weight precompute (independent of CSR build)
  hipLaunchKernelGGL(k1_xw, dim3(K1B), dim3(256), 0, stream, x, en1_w2, en1_b2, xwbuf, xb2);

  // CSR+CSC build: partitioned hist + rank record -> scans -> atomic-free fill
  hipLaunchKernelGGL(k0_hist,  dim3(1024), dim3(256), 0, stream, esrc, edst, outc8, inc8, rankS, rankD);
  hipLaunchKernelGGL(k0_scanA, dim3(100),  dim3(256), 0, stream, outc8, inc8, bsum);
  hipLaunchKernelGGL(k0_scanB, dim3(1),    dim3(128), 0, stream, bsum);
  hipLaunchKernelGGL(k0_scanC, dim3(100),  dim3(256), 0, stream, outc8, inc8, bsum,
                     off, cscoff, base8, cbase8);
  hipLaunchKernelGGL(k0_fill,  dim3(1024), dim3(256), 0, stream, esrc, edst, ea,
                     rankS, rankD, base8, cbase8, erec);

  // layer 1 (MFMA edge kernel)
  hipLaunchKernelGGL(k2_csr,   dim3(1024), dim3(256), 0, stream, erec, en1_w1, en1_b1,
                     xwbuf, xb2, off, msg);
  hipLaunchKernelGGL(k3_node1, dim3(NB3),  dim3(256), 0, stream, x, root1, bias1, msg, cscoff,
                     bn1_g, bn1_b, h1, part1, stats, cnt1);

  // layer 2
  hipLaunchKernelGGL(k6_csr,   dim3(1024), dim3(256), 0, stream, erec, h1, stats,
                     en2_w, en2_b, off, msg);
  hipLaunchKernelGGL(k7_node2, dim3(NB3),  dim3(256), 0, stream, h1, root2, bias2, msg, cscoff,
                     batch, bn2_g, bn2_b, stats, part2, cnt2);

  // head
  hipLaunchKernelGGL(k10_head, dim3(64), dim3(128), 0, stream, stats, mlp_w1, mlp_b1, mlp_w2, mlp_b2, out);
}